// Round 12
// baseline (192.540 us; speedup 1.0000x reference)
//
#include <hip/hip_runtime.h>

#define NGRAPHS 512
#define D 64
#define NCLS 10
#define MAXDEG 64          // Poisson(16) max indegree; P(deg>63)*N ~ 1e-15 — safe pad
#define MDSH 6             // log2(MAXDEG)

// ---- indegree histogram; atomic return value IS the edge's within-node rank ----
__global__ void k_deg(const int* __restrict__ dst, int* __restrict__ degi,
                      int* __restrict__ rank, int E) {
  int i = blockIdx.x * blockDim.x + threadIdx.x;
  if (i < E) rank[i] = atomicAdd(&degi[dst[i]], 1);
}

// ---- fused dispatch 2 (everything that only needs k_deg done):
//      blocks [0,fillBlocks):               ELL fill ec2[dst*64+rank] = {src, tok[src]}
//      blocks [fillBlocks, +disBlocks):     dis = rsqrt(deg+1)
//      remaining blocks:                    ht[v] = emb[v] @ W1  (1000 rows, L2-resident)
__global__ __launch_bounds__(256) void k_fused2(
    const int* __restrict__ src, const int* __restrict__ dst,
    const int* __restrict__ rank, const int* __restrict__ tokens,
    int2* __restrict__ ec2, int E,
    const int* __restrict__ degi, float* __restrict__ dis, int n,
    const float* __restrict__ emb, const float* __restrict__ W1,
    float4* __restrict__ ht4, int ntok, int fillBlocks, int disBlocks,
    int tokBlocks) {
  if (blockIdx.x < fillBlocks) {
    int e = blockIdx.x * 256 + threadIdx.x;
    if (e < E) {
      int s = src[e];
      int rk = rank[e];
      if (rk < MAXDEG)
        ec2[((size_t)dst[e] << MDSH) + rk] = make_int2(s, tokens[s]);
    }
    return;
  }
  if (blockIdx.x < fillBlocks + disBlocks) {
    int i = (blockIdx.x - fillBlocks) * 256 + threadIdx.x;
    if (i < n) dis[i] = rsqrtf((float)degi[i] + 1.0f);
    return;
  }
  // token GEMM: wave per token row; lane=(slot[2b],cg[4b]); slot partitions K
  __shared__ float Ws[64 * 64];
  int tid = threadIdx.x;
  for (int i = tid; i < 64 * 64; i += 256) Ws[i] = W1[i];
  __syncthreads();
  const float4* Ws4 = (const float4*)Ws;
  int w = tid >> 6, lane = tid & 63;
  int cg = lane & 15;
  int kb = lane & 48;
  int bid = blockIdx.x - fillBlocks - disBlocks;
  for (int tok = bid * 4 + w; tok < ntok; tok += tokBlocks * 4) {
    float xval = emb[(size_t)tok * D + lane];
    float4 acc = make_float4(0.f, 0.f, 0.f, 0.f);
#pragma unroll
    for (int p = 0; p < 16; ++p) {
      float xv = __shfl(xval, kb + p, 64);
      float4 wv = Ws4[(kb + p) * 16 + cg];
      acc.x += xv * wv.x; acc.y += xv * wv.y;
      acc.z += xv * wv.z; acc.w += xv * wv.w;
    }
    acc.x += __shfl_xor(acc.x, 16, 64); acc.y += __shfl_xor(acc.y, 16, 64);
    acc.z += __shfl_xor(acc.z, 16, 64); acc.w += __shfl_xor(acc.w, 16, 64);
    acc.x += __shfl_xor(acc.x, 32, 64); acc.y += __shfl_xor(acc.y, 32, 64);
    acc.z += __shfl_xor(acc.z, 32, 64); acc.w += __shfl_xor(acc.w, 32, 64);
    if (lane < 16) ht4[(size_t)tok * 16 + cg] = acc;
  }
}

// ---- layer-1 aggregate over ht (L2-resident) + fused epilogue + fused W2 GEMM:
//      x2'[d] = dis[d] * relu( b1 + dis[d]*(sum_s dis[s]*ht[tok[s]] + dis[d]*ht[tok[d]]) )
//      h2'[d] = x2'[d] @ W2   (written directly; x2' never hits memory) ----
__global__ __launch_bounds__(256) void k_agg1g(const float4* __restrict__ ht4,
                                               const int2* __restrict__ ec2,
                                               const int* __restrict__ degi,
                                               const int* __restrict__ tokens,
                                               const float* __restrict__ dis,
                                               const float4* __restrict__ b14,
                                               const float* __restrict__ W2,
                                               float4* __restrict__ h2, int n) {
  __shared__ float Ws[64 * 64];
  int tid = threadIdx.x;
  for (int i = tid; i < 64 * 64; i += 256) Ws[i] = W2[i];
  __syncthreads();
  const float4* Ws4 = (const float4*)Ws;
  int w = tid >> 6, lane = tid & 63;
  int slot = lane >> 4, cg = lane & 15;
  int kb = lane & 48;
  for (int node = blockIdx.x * 4 + w; node < n; node += gridDim.x * 4) {
    int beg = node << MDSH;
    int end = beg + min(degi[node], MAXDEG);
    float4 acc = make_float4(0.f, 0.f, 0.f, 0.f);
    int j = beg + slot;
    for (; j + 12 < end; j += 16) {     // 4 edges per slot per trip
      int2 e0 = ec2[j], e1 = ec2[j + 4], e2 = ec2[j + 8], e3 = ec2[j + 12];
      float w0 = dis[e0.x], w1 = dis[e1.x], w2 = dis[e2.x], w3 = dis[e3.x];
      float4 v0 = ht4[(size_t)e0.y * 16 + cg];
      float4 v1 = ht4[(size_t)e1.y * 16 + cg];
      float4 v2 = ht4[(size_t)e2.y * 16 + cg];
      float4 v3 = ht4[(size_t)e3.y * 16 + cg];
      acc.x += w0 * v0.x + w1 * v1.x + w2 * v2.x + w3 * v3.x;
      acc.y += w0 * v0.y + w1 * v1.y + w2 * v2.y + w3 * v3.y;
      acc.z += w0 * v0.z + w1 * v1.z + w2 * v2.z + w3 * v3.z;
      acc.w += w0 * v0.w + w1 * v1.w + w2 * v2.w + w3 * v3.w;
    }
    for (; j < end; j += 4) {
      int2 e = ec2[j];
      float wq = dis[e.x];
      float4 v = ht4[(size_t)e.y * 16 + cg];
      acc.x += wq * v.x; acc.y += wq * v.y; acc.z += wq * v.z; acc.w += wq * v.w;
    }
    acc.x += __shfl_xor(acc.x, 16, 64); acc.y += __shfl_xor(acc.y, 16, 64);
    acc.z += __shfl_xor(acc.z, 16, 64); acc.w += __shfl_xor(acc.w, 16, 64);
    acc.x += __shfl_xor(acc.x, 32, 64); acc.y += __shfl_xor(acc.y, 32, 64);
    acc.z += __shfl_xor(acc.z, 32, 64); acc.w += __shfl_xor(acc.w, 32, 64);
    // epilogue on ALL lanes (identical across slots): x2' fragment for this cg
    float dd = dis[node];
    float4 vd = ht4[(size_t)tokens[node] * 16 + cg];
    float4 bv = b14[cg];
    float4 x2;
    x2.x = dd * fmaxf(dd * (acc.x + dd * vd.x) + bv.x, 0.f);
    x2.y = dd * fmaxf(dd * (acc.y + dd * vd.y) + bv.y, 0.f);
    x2.z = dd * fmaxf(dd * (acc.z + dd * vd.z) + bv.z, 0.f);
    x2.w = dd * fmaxf(dd * (acc.w + dd * vd.w) + bv.w, 0.f);
    // GEMM: h2[out4 cg] = sum_k x2[k] * W2[k][..]; this lane covers k in [kb,kb+16)
    float4 g = make_float4(0.f, 0.f, 0.f, 0.f);
#pragma unroll
    for (int p = 0; p < 4; ++p) {
      int sl = (kb >> 2) + p;            // lane holding x2 channels kb+4p .. kb+4p+3
      float xv0 = __shfl(x2.x, sl, 64);
      float xv1 = __shfl(x2.y, sl, 64);
      float xv2 = __shfl(x2.z, sl, 64);
      float xv3 = __shfl(x2.w, sl, 64);
      float4 w0 = Ws4[(kb + 4 * p + 0) * 16 + cg];
      float4 w1 = Ws4[(kb + 4 * p + 1) * 16 + cg];
      float4 w2 = Ws4[(kb + 4 * p + 2) * 16 + cg];
      float4 w3 = Ws4[(kb + 4 * p + 3) * 16 + cg];
      g.x += xv0 * w0.x + xv1 * w1.x + xv2 * w2.x + xv3 * w3.x;
      g.y += xv0 * w0.y + xv1 * w1.y + xv2 * w2.y + xv3 * w3.y;
      g.z += xv0 * w0.z + xv1 * w1.z + xv2 * w2.z + xv3 * w3.z;
      g.w += xv0 * w0.w + xv1 * w1.w + xv2 * w2.w + xv3 * w3.w;
    }
    g.x += __shfl_xor(g.x, 16, 64); g.y += __shfl_xor(g.y, 16, 64);
    g.z += __shfl_xor(g.z, 16, 64); g.w += __shfl_xor(g.w, 16, 64);
    g.x += __shfl_xor(g.x, 32, 64); g.y += __shfl_xor(g.y, 32, 64);
    g.z += __shfl_xor(g.z, 32, 64); g.w += __shfl_xor(g.w, 32, 64);
    if (lane < 16) h2[(size_t)node * 16 + cg] = g;
  }
}

// ---- layer-2 aggregate of h2' + fused epilogue + fused mean-pool accumulation:
//      x3[d] = relu( dis[d]*(sum_s h2'[s] + h2'[d]) + b2 ); sums[batch[d]] += x3[d] ----
__global__ __launch_bounds__(256) void k_aggp(const float4* __restrict__ h4,
                                              const int2* __restrict__ ec2,
                                              const int* __restrict__ degi,
                                              const float* __restrict__ dis,
                                              const float4* __restrict__ b24,
                                              const int* __restrict__ batch,
                                              float* __restrict__ sums, int n) {
  int tid = blockIdx.x * blockDim.x + threadIdx.x;
  int node = tid >> 6;
  int lane = tid & 63;
  int slot = lane >> 4;
  int cg = lane & 15;
  if (node >= n) return;
  int beg = node << MDSH;
  int end = beg + min(degi[node], MAXDEG);
  float4 acc = make_float4(0.f, 0.f, 0.f, 0.f);
  int i = beg + slot;
  for (; i + 12 < end; i += 16) {
    int s0 = ec2[i].x, s1 = ec2[i + 4].x, s2 = ec2[i + 8].x, s3 = ec2[i + 12].x;
    float4 v0 = h4[(size_t)s0 * 16 + cg];
    float4 v1 = h4[(size_t)s1 * 16 + cg];
    float4 v2 = h4[(size_t)s2 * 16 + cg];
    float4 v3 = h4[(size_t)s3 * 16 + cg];
    acc.x += (v0.x + v1.x) + (v2.x + v3.x);
    acc.y += (v0.y + v1.y) + (v2.y + v3.y);
    acc.z += (v0.z + v1.z) + (v2.z + v3.z);
    acc.w += (v0.w + v1.w) + (v2.w + v3.w);
  }
  for (; i < end; i += 4) {
    float4 v = h4[(size_t)ec2[i].x * 16 + cg];
    acc.x += v.x; acc.y += v.y; acc.z += v.z; acc.w += v.w;
  }
  acc.x += __shfl_xor(acc.x, 16, 64); acc.y += __shfl_xor(acc.y, 16, 64);
  acc.z += __shfl_xor(acc.z, 16, 64); acc.w += __shfl_xor(acc.w, 16, 64);
  acc.x += __shfl_xor(acc.x, 32, 64); acc.y += __shfl_xor(acc.y, 32, 64);
  acc.z += __shfl_xor(acc.z, 32, 64); acc.w += __shfl_xor(acc.w, 32, 64);
  if (slot == 0) {
    float dd = dis[node];
    float4 hv = h4[(size_t)node * 16 + cg];
    float4 bv = b24[cg];
    float4 r;
    r.x = fmaxf(dd * (acc.x + hv.x) + bv.x, 0.f);
    r.y = fmaxf(dd * (acc.y + hv.y) + bv.y, 0.f);
    r.z = fmaxf(dd * (acc.z + hv.z) + bv.z, 0.f);
    r.w = fmaxf(dd * (acc.w + hv.w) + bv.w, 0.f);
    float* sp = sums + (size_t)batch[node] * 64 + cg * 4;
    atomicAdd(sp + 0, r.x); atomicAdd(sp + 1, r.y);
    atomicAdd(sp + 2, r.z); atomicAdd(sp + 3, r.w);
  }
}

// ---- head: mean (counts via binary search on sorted batch) + linear ----
__device__ __forceinline__ int lower_bound(const int* __restrict__ a, int n, int v) {
  int lo = 0, hi = n;
  while (lo < hi) {
    int m = (lo + hi) >> 1;
    if (a[m] < v) lo = m + 1; else hi = m;
  }
  return lo;
}

__global__ void k_final(const float* __restrict__ sums, const int* __restrict__ batch,
                        const float* __restrict__ lw, const float* __restrict__ lb,
                        float* __restrict__ out, int n) {
  int i = blockIdx.x * blockDim.x + threadIdx.x;
  if (i >= NGRAPHS * NCLS) return;
  int g = i / NCLS, c = i - g * NCLS;
  int s = lower_bound(batch, n, g);
  int e = lower_bound(batch, n, g + 1);
  float inv = 1.0f / fmaxf((float)(e - s), 1.0f);
  float a = lb[c];
#pragma unroll
  for (int k = 0; k < D; ++k) a += sums[g * 64 + k] * inv * lw[k * NCLS + c];
  out[i] = a;
}

extern "C" void kernel_launch(void* const* d_in, const int* in_sizes, int n_in,
                              void* d_out, int out_size, void* d_ws, size_t ws_size,
                              hipStream_t stream) {
  const int* tokens = (const int*)d_in[0];
  const int* edge   = (const int*)d_in[1];
  const int* batch  = (const int*)d_in[2];
  const float* emb  = (const float*)d_in[3];
  const float* W1   = (const float*)d_in[4];
  const float* b1   = (const float*)d_in[5];
  const float* W2   = (const float*)d_in[6];
  const float* b2   = (const float*)d_in[7];
  const float* lw   = (const float*)d_in[8];
  const float* lb   = (const float*)d_in[9];
  float* out = (float*)d_out;

  const int N = in_sizes[0];
  const int E = in_sizes[1] / 2;
  const int ntok = in_sizes[3] / D;
  const int* src  = edge;
  const int* dstv = edge + E;

  char* ws = (char*)d_ws;
  size_t off = 0;
  auto alloc = [&](size_t bytes) {
    void* p = ws + off;
    off += (bytes + 255) & ~(size_t)255;
    return p;
  };
  float* A    = (float*)alloc((size_t)N * D * sizeof(float));       // h2'
  int2*  ec2  = (int2*)alloc((size_t)N * MAXDEG * sizeof(int2));     // ELL {src, tok}
  int*   rank = (int*)alloc((size_t)E * sizeof(int));                // within-node slot
  float* dis  = (float*)alloc((size_t)N * sizeof(float));
  int*   degi = (int*)alloc((size_t)N * sizeof(int));                // \ contiguous:
  float* sums = (float*)alloc((size_t)NGRAPHS * D * sizeof(float));  // / one memset
  float* ht   = (float*)alloc((size_t)ntok * D * sizeof(float));     // emb @ W1

  // single memset covers degi + sums (adjacent allocations)
  size_t zbytes = (size_t)(((char*)sums + (size_t)NGRAPHS * D * sizeof(float)) - (char*)degi);
  hipMemsetAsync(degi, 0, zbytes, stream);

  // 1) indegree + per-edge rank
  k_deg<<<(E + 255) / 256, 256, 0, stream>>>(dstv, degi, rank, E);

  // 2) fused: ELL fill + dis + token GEMM (ht = emb @ W1)
  const int fillBlocks = (E + 255) / 256;
  const int disBlocks = (N + 255) / 256;
  const int tokBlocks = (ntok + 3) / 4;
  k_fused2<<<fillBlocks + disBlocks + tokBlocks, 256, 0, stream>>>(
      src, dstv, rank, tokens, ec2, E, degi, dis, N, emb, W1, (float4*)ht, ntok,
      fillBlocks, disBlocks, tokBlocks);

  // 3) layer-1 aggregate + epilogue + W2 GEMM fused -> h2' in A
  k_agg1g<<<2048, 256, 0, stream>>>((const float4*)ht, ec2, degi, tokens, dis,
                                    (const float4*)b1, W2, (float4*)A, N);

  // 4) layer-2 aggregate + epilogue + pool accumulation -> sums
  const int nodeBlocks = (N + 3) / 4;
  k_aggp<<<nodeBlocks, 256, 0, stream>>>((const float4*)A, ec2, degi, dis,
                                         (const float4*)b2, batch, sums, N);

  // 5) head
  k_final<<<(NGRAPHS * NCLS + 255) / 256, 256, 0, stream>>>(sums, batch, lw, lb, out, N);
}

// Round 13
// 157.554 us; speedup vs baseline: 1.2221x; 1.2221x over previous
//
#include <hip/hip_runtime.h>

#define NGRAPHS 512
#define D 64
#define NCLS 10
#define MAXDEG 64          // Poisson(16) max indegree; P(deg>63)*N ~ 1e-15 — safe pad
#define MDSH 6             // log2(MAXDEG)

// ---- indegree histogram; atomic return value IS the edge's within-node rank ----
__global__ void k_deg(const int* __restrict__ dst, int* __restrict__ degi,
                      int* __restrict__ rank, int E) {
  int i = blockIdx.x * blockDim.x + threadIdx.x;
  if (i < E) rank[i] = atomicAdd(&degi[dst[i]], 1);
}

// ---- fused dispatch 2 (everything that only needs k_deg done):
//      blocks [0,fillBlocks):               ELL fill ec2[dst*64+rank] = {src, tok[src]}
//      blocks [fillBlocks, +disBlocks):     dis = rsqrt(deg+1); zero pad rows; dis[n]=0
//      remaining blocks:                    ht[v] = emb[v] @ W1  (1000 rows, L2-resident)
__global__ __launch_bounds__(256) void k_fused2(
    const int* __restrict__ src, const int* __restrict__ dst,
    const int* __restrict__ rank, const int* __restrict__ tokens,
    int2* __restrict__ ec2, int E,
    const int* __restrict__ degi, float* __restrict__ dis, int n,
    const float* __restrict__ emb, const float* __restrict__ W1,
    float4* __restrict__ ht4, float4* __restrict__ h2pad, int ntok,
    int fillBlocks, int disBlocks, int tokBlocks) {
  if (blockIdx.x < fillBlocks) {
    int e = blockIdx.x * 256 + threadIdx.x;
    if (e < E) {
      int s = src[e];
      int rk = rank[e];
      if (rk < MAXDEG)
        ec2[((size_t)dst[e] << MDSH) + rk] = make_int2(s, tokens[s]);
    }
    return;
  }
  if (blockIdx.x < fillBlocks + disBlocks) {
    int i = (blockIdx.x - fillBlocks) * 256 + threadIdx.x;
    if (i < n) dis[i] = rsqrtf((float)degi[i] + 1.0f);
    if (blockIdx.x == fillBlocks) {
      int t = threadIdx.x;
      if (t == 0) dis[n] = 0.0f;                       // pad weight for layer-1 gather
      float4 z = make_float4(0.f, 0.f, 0.f, 0.f);
      if (t < 16) h2pad[((size_t)n << 4) + t] = z;     // zero row n of h2' (aggs pad)
      else if (t < 32) ht4[((size_t)ntok << 4) + (t - 16)] = z;  // zero row ntok of ht
    }
    return;
  }
  // token GEMM: wave per token row; lane=(slot[2b],cg[4b]); slot partitions K
  __shared__ float Ws[64 * 64];
  int tid = threadIdx.x;
  for (int i = tid; i < 64 * 64; i += 256) Ws[i] = W1[i];
  __syncthreads();
  const float4* Ws4 = (const float4*)Ws;
  int w = tid >> 6, lane = tid & 63;
  int cg = lane & 15;
  int kb = lane & 48;
  int bid = blockIdx.x - fillBlocks - disBlocks;
  for (int tok = bid * 4 + w; tok < ntok; tok += tokBlocks * 4) {
    float xval = emb[(size_t)tok * D + lane];
    float4 acc = make_float4(0.f, 0.f, 0.f, 0.f);
#pragma unroll
    for (int p = 0; p < 16; ++p) {
      float xv = __shfl(xval, kb + p, 64);
      float4 wv = Ws4[(kb + p) * 16 + cg];
      acc.x += xv * wv.x; acc.y += xv * wv.y;
      acc.z += xv * wv.z; acc.w += xv * wv.w;
    }
    acc.x += __shfl_xor(acc.x, 16, 64); acc.y += __shfl_xor(acc.y, 16, 64);
    acc.z += __shfl_xor(acc.z, 16, 64); acc.w += __shfl_xor(acc.w, 16, 64);
    acc.x += __shfl_xor(acc.x, 32, 64); acc.y += __shfl_xor(acc.y, 32, 64);
    acc.z += __shfl_xor(acc.z, 32, 64); acc.w += __shfl_xor(acc.w, 32, 64);
    if (lane < 16) ht4[(size_t)tok * 16 + cg] = acc;
  }
}

// ---- layer-1 aggregate over ht (L2-resident) + epilogue + fused W2 GEMM.
//      Single-round gather: 4 slots x 8 unrolled loads = 32 edges/trip, predicated
//      pads (s->n with dis[n]=0, t->ntok zero row). h2' written directly. ----
__global__ __launch_bounds__(256) void k_agg1g(const float4* __restrict__ ht4,
                                               const int2* __restrict__ ec2,
                                               const int* __restrict__ degi,
                                               const int* __restrict__ tokens,
                                               const float* __restrict__ dis,
                                               const float4* __restrict__ b14,
                                               const float* __restrict__ W2,
                                               float4* __restrict__ h2, int n,
                                               int ntok) {
  __shared__ float Ws[64 * 64];
  int tid = threadIdx.x;
  for (int i = tid; i < 64 * 64; i += 256) Ws[i] = W2[i];
  __syncthreads();
  const float4* Ws4 = (const float4*)Ws;
  int w = tid >> 6, lane = tid & 63;
  int slot = lane >> 4, cg = lane & 15;
  int kb = lane & 48;
  for (int node = blockIdx.x * 4 + w; node < n; node += gridDim.x * 4) {
    int deg = min(degi[node], MAXDEG);
    int beg = node << MDSH;
    int endp = beg + deg;
    float4 acc = make_float4(0.f, 0.f, 0.f, 0.f);
    int rounds = (deg + 31) >> 5;     // 1 for deg<=32 (99.99%), 2 otherwise
    int j = beg + slot;
    for (int r = 0; r < rounds; ++r, j += 32) {
      int i0 = j, i1 = j + 4, i2 = j + 8, i3 = j + 12,
          i4 = j + 16, i5 = j + 20, i6 = j + 24, i7 = j + 28;
      int2 e0 = ec2[i0], e1 = ec2[i1], e2 = ec2[i2], e3 = ec2[i3];
      int2 e4 = ec2[i4], e5 = ec2[i5], e6 = ec2[i6], e7 = ec2[i7];
      int s0 = i0 < endp ? e0.x : n, t0 = i0 < endp ? e0.y : ntok;
      int s1 = i1 < endp ? e1.x : n, t1 = i1 < endp ? e1.y : ntok;
      int s2 = i2 < endp ? e2.x : n, t2 = i2 < endp ? e2.y : ntok;
      int s3 = i3 < endp ? e3.x : n, t3 = i3 < endp ? e3.y : ntok;
      int s4 = i4 < endp ? e4.x : n, t4 = i4 < endp ? e4.y : ntok;
      int s5 = i5 < endp ? e5.x : n, t5 = i5 < endp ? e5.y : ntok;
      int s6 = i6 < endp ? e6.x : n, t6 = i6 < endp ? e6.y : ntok;
      int s7 = i7 < endp ? e7.x : n, t7 = i7 < endp ? e7.y : ntok;
      float w0 = dis[s0], w1 = dis[s1], w2 = dis[s2], w3 = dis[s3];
      float w4 = dis[s4], w5 = dis[s5], w6 = dis[s6], w7 = dis[s7];
      float4 v0 = ht4[((size_t)t0 << 4) + cg];
      float4 v1 = ht4[((size_t)t1 << 4) + cg];
      float4 v2 = ht4[((size_t)t2 << 4) + cg];
      float4 v3 = ht4[((size_t)t3 << 4) + cg];
      float4 v4 = ht4[((size_t)t4 << 4) + cg];
      float4 v5 = ht4[((size_t)t5 << 4) + cg];
      float4 v6 = ht4[((size_t)t6 << 4) + cg];
      float4 v7 = ht4[((size_t)t7 << 4) + cg];
      acc.x += w0 * v0.x + w1 * v1.x + w2 * v2.x + w3 * v3.x
             + w4 * v4.x + w5 * v5.x + w6 * v6.x + w7 * v7.x;
      acc.y += w0 * v0.y + w1 * v1.y + w2 * v2.y + w3 * v3.y
             + w4 * v4.y + w5 * v5.y + w6 * v6.y + w7 * v7.y;
      acc.z += w0 * v0.z + w1 * v1.z + w2 * v2.z + w3 * v3.z
             + w4 * v4.z + w5 * v5.z + w6 * v6.z + w7 * v7.z;
      acc.w += w0 * v0.w + w1 * v1.w + w2 * v2.w + w3 * v3.w
             + w4 * v4.w + w5 * v5.w + w6 * v6.w + w7 * v7.w;
    }
    acc.x += __shfl_xor(acc.x, 16, 64); acc.y += __shfl_xor(acc.y, 16, 64);
    acc.z += __shfl_xor(acc.z, 16, 64); acc.w += __shfl_xor(acc.w, 16, 64);
    acc.x += __shfl_xor(acc.x, 32, 64); acc.y += __shfl_xor(acc.y, 32, 64);
    acc.z += __shfl_xor(acc.z, 32, 64); acc.w += __shfl_xor(acc.w, 32, 64);
    // epilogue on ALL lanes (identical across slots): x2' fragment for this cg
    float dd = dis[node];
    float4 vd = ht4[((size_t)tokens[node] << 4) + cg];
    float4 bv = b14[cg];
    float4 x2;
    x2.x = dd * fmaxf(dd * (acc.x + dd * vd.x) + bv.x, 0.f);
    x2.y = dd * fmaxf(dd * (acc.y + dd * vd.y) + bv.y, 0.f);
    x2.z = dd * fmaxf(dd * (acc.z + dd * vd.z) + bv.z, 0.f);
    x2.w = dd * fmaxf(dd * (acc.w + dd * vd.w) + bv.w, 0.f);
    // GEMM: h2[node] = x2 @ W2; this lane covers k in [kb, kb+16)
    float4 g = make_float4(0.f, 0.f, 0.f, 0.f);
#pragma unroll
    for (int p = 0; p < 4; ++p) {
      int sl = (kb >> 2) + p;            // lane holding x2 channels kb+4p .. kb+4p+3
      float xv0 = __shfl(x2.x, sl, 64);
      float xv1 = __shfl(x2.y, sl, 64);
      float xv2 = __shfl(x2.z, sl, 64);
      float xv3 = __shfl(x2.w, sl, 64);
      float4 w0 = Ws4[(kb + 4 * p + 0) * 16 + cg];
      float4 w1 = Ws4[(kb + 4 * p + 1) * 16 + cg];
      float4 w2 = Ws4[(kb + 4 * p + 2) * 16 + cg];
      float4 w3 = Ws4[(kb + 4 * p + 3) * 16 + cg];
      g.x += xv0 * w0.x + xv1 * w1.x + xv2 * w2.x + xv3 * w3.x;
      g.y += xv0 * w0.y + xv1 * w1.y + xv2 * w2.y + xv3 * w3.y;
      g.z += xv0 * w0.z + xv1 * w1.z + xv2 * w2.z + xv3 * w3.z;
      g.w += xv0 * w0.w + xv1 * w1.w + xv2 * w2.w + xv3 * w3.w;
    }
    g.x += __shfl_xor(g.x, 16, 64); g.y += __shfl_xor(g.y, 16, 64);
    g.z += __shfl_xor(g.z, 16, 64); g.w += __shfl_xor(g.w, 16, 64);
    g.x += __shfl_xor(g.x, 32, 64); g.y += __shfl_xor(g.y, 32, 64);
    g.z += __shfl_xor(g.z, 32, 64); g.w += __shfl_xor(g.w, 32, 64);
    if (lane < 16) h2[((size_t)node << 4) + cg] = g;
  }
}

// ---- layer-2 aggregate of h2' + fused epilogue -> x3. Single-round gather:
//      predicated pad index -> zeroed row n of h2'. ----
__global__ __launch_bounds__(256) void k_aggs(const float4* __restrict__ h4,
                                              const int2* __restrict__ ec2,
                                              const int* __restrict__ degi,
                                              const float* __restrict__ dis,
                                              const float4* __restrict__ b24,
                                              float4* __restrict__ out, int n) {
  int tid = blockIdx.x * blockDim.x + threadIdx.x;
  int node = tid >> 6;
  int lane = tid & 63;
  int slot = lane >> 4;
  int cg = lane & 15;
  if (node >= n) return;
  int deg = min(degi[node], MAXDEG);
  int beg = node << MDSH;
  int endp = beg + deg;
  float4 acc = make_float4(0.f, 0.f, 0.f, 0.f);
  int rounds = (deg + 31) >> 5;
  int j = beg + slot;
  for (int r = 0; r < rounds; ++r, j += 32) {
    int i0 = j, i1 = j + 4, i2 = j + 8, i3 = j + 12,
        i4 = j + 16, i5 = j + 20, i6 = j + 24, i7 = j + 28;
    int2 e0 = ec2[i0], e1 = ec2[i1], e2 = ec2[i2], e3 = ec2[i3];
    int2 e4 = ec2[i4], e5 = ec2[i5], e6 = ec2[i6], e7 = ec2[i7];
    int s0 = i0 < endp ? e0.x : n;
    int s1 = i1 < endp ? e1.x : n;
    int s2 = i2 < endp ? e2.x : n;
    int s3 = i3 < endp ? e3.x : n;
    int s4 = i4 < endp ? e4.x : n;
    int s5 = i5 < endp ? e5.x : n;
    int s6 = i6 < endp ? e6.x : n;
    int s7 = i7 < endp ? e7.x : n;
    float4 v0 = h4[((size_t)s0 << 4) + cg];
    float4 v1 = h4[((size_t)s1 << 4) + cg];
    float4 v2 = h4[((size_t)s2 << 4) + cg];
    float4 v3 = h4[((size_t)s3 << 4) + cg];
    float4 v4 = h4[((size_t)s4 << 4) + cg];
    float4 v5 = h4[((size_t)s5 << 4) + cg];
    float4 v6 = h4[((size_t)s6 << 4) + cg];
    float4 v7 = h4[((size_t)s7 << 4) + cg];
    acc.x += ((v0.x + v1.x) + (v2.x + v3.x)) + ((v4.x + v5.x) + (v6.x + v7.x));
    acc.y += ((v0.y + v1.y) + (v2.y + v3.y)) + ((v4.y + v5.y) + (v6.y + v7.y));
    acc.z += ((v0.z + v1.z) + (v2.z + v3.z)) + ((v4.z + v5.z) + (v6.z + v7.z));
    acc.w += ((v0.w + v1.w) + (v2.w + v3.w)) + ((v4.w + v5.w) + (v6.w + v7.w));
  }
  acc.x += __shfl_xor(acc.x, 16, 64); acc.y += __shfl_xor(acc.y, 16, 64);
  acc.z += __shfl_xor(acc.z, 16, 64); acc.w += __shfl_xor(acc.w, 16, 64);
  acc.x += __shfl_xor(acc.x, 32, 64); acc.y += __shfl_xor(acc.y, 32, 64);
  acc.z += __shfl_xor(acc.z, 32, 64); acc.w += __shfl_xor(acc.w, 32, 64);
  if (slot == 0) {
    float dd = dis[node];
    float4 hv = h4[((size_t)node << 4) + cg];
    float4 bv = b24[cg];
    acc.x = fmaxf(dd * (acc.x + hv.x) + bv.x, 0.f);
    acc.y = fmaxf(dd * (acc.y + hv.y) + bv.y, 0.f);
    acc.z = fmaxf(dd * (acc.z + hv.z) + bv.z, 0.f);
    acc.w = fmaxf(dd * (acc.w + hv.w) + bv.w, 0.f);
    out[((size_t)node << 4) + cg] = acc;
  }
}

// ---- fused mean-pool + linear head: one block per graph ----
__device__ __forceinline__ int lower_bound(const int* __restrict__ a, int n, int v) {
  int lo = 0, hi = n;
  while (lo < hi) {
    int m = (lo + hi) >> 1;
    if (a[m] < v) lo = m + 1; else hi = m;
  }
  return lo;
}

__global__ __launch_bounds__(256) void k_poolfinal(const float* __restrict__ x,
                                                   const int* __restrict__ batch,
                                                   const float* __restrict__ lw,
                                                   const float* __restrict__ lb,
                                                   float* __restrict__ out, int n) {
  __shared__ float red[4][64];
  __shared__ float pooled[64];
  int g = blockIdx.x;
  int s = lower_bound(batch, n, g);
  int e = lower_bound(batch, n, g + 1);
  int w = threadIdx.x >> 6, lane = threadIdx.x & 63;
  float acc = 0.f;
  for (int i = s + w; i < e; i += 4) acc += x[(size_t)i * D + lane];
  red[w][lane] = acc;
  __syncthreads();
  if (w == 0) {
    float v = red[0][lane] + red[1][lane] + red[2][lane] + red[3][lane];
    pooled[lane] = v / fmaxf((float)(e - s), 1.0f);
  }
  __syncthreads();
  if (threadIdx.x < NCLS) {
    int c = threadIdx.x;
    float a = lb[c];
#pragma unroll
    for (int k = 0; k < D; ++k) a += pooled[k] * lw[k * NCLS + c];
    out[g * NCLS + c] = a;
  }
}

extern "C" void kernel_launch(void* const* d_in, const int* in_sizes, int n_in,
                              void* d_out, int out_size, void* d_ws, size_t ws_size,
                              hipStream_t stream) {
  const int* tokens = (const int*)d_in[0];
  const int* edge   = (const int*)d_in[1];
  const int* batch  = (const int*)d_in[2];
  const float* emb  = (const float*)d_in[3];
  const float* W1   = (const float*)d_in[4];
  const float* b1   = (const float*)d_in[5];
  const float* W2   = (const float*)d_in[6];
  const float* b2   = (const float*)d_in[7];
  const float* lw   = (const float*)d_in[8];
  const float* lb   = (const float*)d_in[9];
  float* out = (float*)d_out;

  const int N = in_sizes[0];
  const int E = in_sizes[1] / 2;
  const int ntok = in_sizes[3] / D;
  const int* src  = edge;
  const int* dstv = edge + E;

  char* ws = (char*)d_ws;
  size_t off = 0;
  auto alloc = [&](size_t bytes) {
    void* p = ws + off;
    off += (bytes + 255) & ~(size_t)255;
    return p;
  };
  float* A    = (float*)alloc((size_t)(N + 1) * D * sizeof(float));  // h2' (+pad row)
  float* B    = (float*)alloc((size_t)N * D * sizeof(float));        // x3
  int2*  ec2  = (int2*)alloc((size_t)N * MAXDEG * sizeof(int2));      // ELL {src, tok}
  int*   rank = (int*)alloc((size_t)E * sizeof(int));                 // within-node slot
  float* dis  = (float*)alloc((size_t)(N + 1) * sizeof(float));       // +pad entry
  int*   degi = (int*)alloc((size_t)N * sizeof(int));
  float* ht   = (float*)alloc((size_t)(ntok + 1) * D * sizeof(float)); // emb@W1 (+pad)

  hipMemsetAsync(degi, 0, (size_t)N * sizeof(int), stream);

  // 1) indegree + per-edge rank
  k_deg<<<(E + 255) / 256, 256, 0, stream>>>(dstv, degi, rank, E);

  // 2) fused: ELL fill + dis/pad-rows + token GEMM (ht = emb @ W1)
  const int fillBlocks = (E + 255) / 256;
  const int disBlocks = (N + 255) / 256;
  const int tokBlocks = (ntok + 3) / 4;
  k_fused2<<<fillBlocks + disBlocks + tokBlocks, 256, 0, stream>>>(
      src, dstv, rank, tokens, ec2, E, degi, dis, N, emb, W1, (float4*)ht,
      (float4*)A, ntok, fillBlocks, disBlocks, tokBlocks);

  // 3) layer-1 aggregate (single-round, predicated) + epilogue + W2 GEMM -> h2' in A
  k_agg1g<<<2048, 256, 0, stream>>>((const float4*)ht, ec2, degi, tokens, dis,
                                    (const float4*)b1, W2, (float4*)A, N, ntok);

  // 4) layer-2 aggregate (single-round, predicated) + epilogue -> x3 in B
  const int nodeBlocks = (N + 3) / 4;
  k_aggs<<<nodeBlocks, 256, 0, stream>>>((const float4*)A, ec2, degi, dis,
                                         (const float4*)b2, (float4*)B, N);

  // 5) pooling + head
  k_poolfinal<<<NGRAPHS, 256, 0, stream>>>(B, batch, lw, lb, out, N);
}